// Round 7
// baseline (193.426 us; speedup 1.0000x reference)
//
#include <hip/hip_runtime.h>
#include <math.h>

#define B_  4
#define C_  256
#define N_  4096
#define NT  (N_ / 64)
#define LOG2E 1.44269504088896f

typedef __attribute__((ext_vector_type(8)))  short v8s;
typedef __attribute__((ext_vector_type(4)))  float v4f;
typedef __attribute__((ext_vector_type(16))) float v16f;

__device__ inline unsigned short f2bf(float f) {
    unsigned u = __builtin_bit_cast(unsigned, f);
    unsigned r = (u + 0x7fffu + ((u >> 16) & 1u)) >> 16;
    return (unsigned short)r;
}
__device__ inline unsigned cvtpk(float lo, float hi) {
    unsigned r;
    asm("v_cvt_pk_bf16_f32 %0, %1, %2" : "=v"(r) : "v"(lo), "v"(hi));
    return r;
}
__device__ inline void swap32(unsigned &a, unsigned &b) {
    asm volatile("v_permlane32_swap_b32 %0, %1" : "+v"(a), "+v"(b));
}
__device__ inline void gl_lds16(const void* g, void* l) {
    __builtin_amdgcn_global_load_lds(
        (const __attribute__((address_space(1))) unsigned*)g,
        (__attribute__((address_space(3))) unsigned*)l, 16, 0, 0);
}

// ---------------- W convert ----------------
__global__ __launch_bounds__(256) void wcvt_kernel(
    const float* __restrict__ Wb, const float* __restrict__ Wc,
    const float* __restrict__ Wd, unsigned short* __restrict__ Wcat)
{
    int i = (blockIdx.x * 256 + threadIdx.x) * 4;
    int row = i >> 8, col = i & 255;
    const float* src;
    if (row < 256)      src = Wd + row * 256 + col;
    else if (row < 288) src = Wb + (row - 256) * 256 + col;
    else                src = Wc + (row - 288) * 256 + col;
    float4 v = *(const float4*)src;
    uint2 p;
    p.x = cvtpk(v.x, v.y);
    p.y = cvtpk(v.z, v.w);
    *(uint2*)(Wcat + i) = p;
}

// ---------------- MFMA projection ----------------
#define PXS 264
__global__ __launch_bounds__(256, 2) void proj_mfma(
    const float* __restrict__ x, const unsigned short* __restrict__ Wcat,
    const float* __restrict__ bb, const float* __restrict__ bc,
    const float* __restrict__ bd,
    unsigned short* __restrict__ Q, unsigned short* __restrict__ K,
    unsigned short* __restrict__ V)
{
    __shared__ unsigned short Xs[32][PXS];
    const int t = threadIdx.x;
    const int w = t >> 6, l = t & 63, l16 = l & 15, lg = l >> 4;
    const int n0 = blockIdx.x * 32, b = blockIdx.y;

    // coalesced float4 staging along N + LDS transpose
    {
        const int n4 = (t & 7) * 4, cb = t >> 3;
        const float* xp = x + (size_t)b * C_ * N_ + n0 + n4;
#pragma unroll
        for (int r = 0; r < 8; r++) {
            const int c = cb + r * 32;
            float4 v = *(const float4*)(xp + (size_t)c * N_);
            Xs[n4 + 0][c] = f2bf(v.x);
            Xs[n4 + 1][c] = f2bf(v.y);
            Xs[n4 + 2][c] = f2bf(v.z);
            Xs[n4 + 3][c] = f2bf(v.w);
        }
    }
    __syncthreads();

#pragma unroll 1
    for (int si = 0; si < 5; si++) {
        const int sub = w * 5 + si;
        v8s aw[8];
#pragma unroll
        for (int kk = 0; kk < 8; kk++)
            aw[kk] = *(const v8s*)(Wcat + (size_t)(sub * 16 + l16) * 256 + kk * 32 + lg * 8);

        v4f acc[2];
#pragma unroll
        for (int ns = 0; ns < 2; ns++) { v4f z = {0.f,0.f,0.f,0.f}; acc[ns] = z; }
#pragma unroll
        for (int kk = 0; kk < 8; kk++)
#pragma unroll
            for (int ns = 0; ns < 2; ns++) {
                v8s bx = *(const v8s*)&Xs[ns * 16 + l16][kk * 32 + lg * 8];
                acc[ns] = __builtin_amdgcn_mfma_f32_16x16x32_bf16(aw[kk], bx, acc[ns], 0, 0, 0);
            }

        if (sub < 16) {
            float bi[4];
#pragma unroll
            for (int r = 0; r < 4; r++) bi[r] = bd[sub * 16 + lg * 4 + r];
#pragma unroll
            for (int ns = 0; ns < 2; ns++) {
                const int n = n0 + ns * 16 + l16;
#pragma unroll
                for (int r = 0; r < 4; r++) {
                    int c = sub * 16 + lg * 4 + r;
                    V[((size_t)b * C_ + c) * N_ + n] = f2bf(acc[ns][r] + bi[r]);
                }
            }
        } else {
            const int qk = sub - 16;              // 0,1 -> Q ; 2,3 -> K
            const bool isQ = (qk < 2);
            const int o0l = (qk & 1) * 16;
            const float* bias = isQ ? bb : bc;
            unsigned short* dst = isQ ? Q : K;
            const float scl = isQ ? LOG2E : 1.0f; // Q pre-scaled -> attn uses exp2
            float bi[4];
#pragma unroll
            for (int r = 0; r < 4; r++) bi[r] = bias[o0l + lg * 4 + r];
#pragma unroll
            for (int ns = 0; ns < 2; ns++) {
                const int n = n0 + ns * 16 + l16;
                uint2 pk;
                pk.x = cvtpk((acc[ns][0] + bi[0]) * scl, (acc[ns][1] + bi[1]) * scl);
                pk.y = cvtpk((acc[ns][2] + bi[2]) * scl, (acc[ns][3] + bi[3]) * scl);
                *(uint2*)(dst + ((size_t)b * N_ + n) * 32 + o0l + lg * 4) = pk;
            }
        }
    }
}

// ---------------- 32x32-MFMA flash attention, P pipelined one iteration ----------------
__global__ __launch_bounds__(256, 2) void attn_mfma(
    const unsigned short* __restrict__ Qg, const unsigned short* __restrict__ Kg,
    const unsigned short* __restrict__ Vg, const float* __restrict__ x,
    const float* __restrict__ gamma, float* __restrict__ out)
{
    __shared__ unsigned short Vs[4][64][64];   // 4-deep ring, slot-swizzled

    const int t = threadIdx.x, l = t & 63, cl = l & 31, h = l >> 5;
    const int qs = t >> 6;
    const int i = blockIdx.x;
    const int xcd = i & 7, b = xcd >> 1, ch_hi = xcd & 1;
    const int rdec = i >> 3, ch = ch_hi * 2 + (rdec & 1), qb = rdec >> 1;
    const int q0 = qb * 128;
    const int q = q0 + qs * 32 + cl;

    const unsigned short* qp = Qg + ((size_t)b * N_ + q) * 32 + h * 8;
    const v8s bQ0 = *(const v8s*)(qp);
    const v8s bQ1 = *(const v8s*)(qp + 16);

    const unsigned short* kp = Kg + ((size_t)b * N_ + cl) * 32 + h * 8;
    const unsigned short* Vb = Vg + ((size_t)b * C_ + ch * 64) * N_;
    const int vrow = t >> 3;
    const int vslot = (t & 7) ^ (vrow & 7);
    const unsigned short* vsrc0 = Vb + (size_t)vrow * N_ + vslot * 8;
    const unsigned short* vsrc1 = Vb + (size_t)(32 + vrow) * N_ + vslot * 8;
    const int wofs = (t >> 6) * 1024;

    v16f acc0, acc1;
#pragma unroll
    for (int r = 0; r < 16; r++) { acc0[r] = 0.f; acc1[r] = 0.f; }
    float l_lane = 0.f;

    // prologue: DMA tile 0 -> buf 0; K frags tile 0
    gl_lds16(vsrc0, (char*)&Vs[0][0][0] + wofs);
    gl_lds16(vsrc1, (char*)&Vs[0][0][0] + wofs + 4096);
    v8s kc0a = *(const v8s*)(kp);
    v8s kc0b = *(const v8s*)(kp + 16);
    v8s kc1a = *(const v8s*)(kp + 1024);
    v8s kc1b = *(const v8s*)(kp + 1024 + 16);
    __syncthreads();

    const int sx0 = ((0 + h) ^ (l & 7)) << 4;   // ks2 slot xor row-swizzle
    const int sx1 = ((2 + h) ^ (l & 7)) << 4;
    const int sx2 = ((4 + h) ^ (l & 7)) << 4;
    const int sx3 = ((6 + h) ^ (l & 7)) << 4;

    v8s pbP0, pbP1, pbP2, pbP3;   // prev-iter PV B-frags (ks2 = 0..3)

#pragma unroll 1
    for (int it = 0; it < NT; it++) {
        v8s kn0a, kn0b, kn1a, kn1b;
        if (it + 1 < NT) {
            const int m1 = (it + 1) * 64;
            char* vd = (char*)&Vs[(it + 1) & 3][0][0] + wofs;
            gl_lds16(vsrc0 + m1, vd);
            gl_lds16(vsrc1 + m1, vd + 4096);
            const unsigned short* kpm = kp + (size_t)m1 * 32;
            kn0a = *(const v8s*)(kpm);
            kn0b = *(const v8s*)(kpm + 16);
            kn1a = *(const v8s*)(kpm + 1024);
            kn1b = *(const v8s*)(kpm + 1024 + 16);
        }

        // ---- S^T(it) ----
        v16f st0, st1;
#pragma unroll
        for (int r = 0; r < 16; r++) { st0[r] = 0.f; st1[r] = 0.f; }
        st0 = __builtin_amdgcn_mfma_f32_32x32x16_bf16(kc0a, bQ0, st0, 0, 0, 0);
        st0 = __builtin_amdgcn_mfma_f32_32x32x16_bf16(kc0b, bQ1, st0, 0, 0, 0);
        st1 = __builtin_amdgcn_mfma_f32_32x32x16_bf16(kc1a, bQ0, st1, 0, 0, 0);
        st1 = __builtin_amdgcn_mfma_f32_32x32x16_bf16(kc1b, bQ1, st1, 0, 0, 0);

        // ---- PV(it-1): independent of exp chain; overlaps it in the pipes ----
        if (it > 0) {
            const char* vbse = (const char*)&Vs[(it - 1) & 3][0][0];
            v8s a00 = *(const v8s*)(vbse + (cl << 7) + sx0);
            v8s a10 = *(const v8s*)(vbse + ((32 + cl) << 7) + sx0);
            v8s a01 = *(const v8s*)(vbse + (cl << 7) + sx1);
            v8s a11 = *(const v8s*)(vbse + ((32 + cl) << 7) + sx1);
            v8s a02 = *(const v8s*)(vbse + (cl << 7) + sx2);
            v8s a12 = *(const v8s*)(vbse + ((32 + cl) << 7) + sx2);
            v8s a03 = *(const v8s*)(vbse + (cl << 7) + sx3);
            v8s a13 = *(const v8s*)(vbse + ((32 + cl) << 7) + sx3);
            acc0 = __builtin_amdgcn_mfma_f32_32x32x16_bf16(a00, pbP0, acc0, 0, 0, 0);
            acc1 = __builtin_amdgcn_mfma_f32_32x32x16_bf16(a10, pbP0, acc1, 0, 0, 0);
            acc0 = __builtin_amdgcn_mfma_f32_32x32x16_bf16(a01, pbP1, acc0, 0, 0, 0);
            acc1 = __builtin_amdgcn_mfma_f32_32x32x16_bf16(a11, pbP1, acc1, 0, 0, 0);
            acc0 = __builtin_amdgcn_mfma_f32_32x32x16_bf16(a02, pbP2, acc0, 0, 0, 0);
            acc1 = __builtin_amdgcn_mfma_f32_32x32x16_bf16(a12, pbP2, acc1, 0, 0, 0);
            acc0 = __builtin_amdgcn_mfma_f32_32x32x16_bf16(a03, pbP3, acc0, 0, 0, 0);
            acc1 = __builtin_amdgcn_mfma_f32_32x32x16_bf16(a13, pbP3, acc1, 0, 0, 0);
        }

        // ---- raw exp2 (Q pre-scaled by log2e) ----
        float ps = 0.f;
#pragma unroll
        for (int r = 0; r < 16; r++) { st0[r] = exp2f(st0[r]); ps += st0[r]; }
#pragma unroll
        for (int r = 0; r < 16; r++) { st1[r] = exp2f(st1[r]); ps += st1[r]; }
        l_lane += ps;

        // ---- pack P(it) -> B-frags for next iteration's PV ----
        unsigned pbw[4][4];
#pragma unroll
        for (int ms = 0; ms < 2; ms++) {
#pragma unroll
            for (int kl = 0; kl < 2; kl++) {
#pragma unroll
                for (int wl = 0; wl < 2; wl++) {
                    float e0, e1, f0, f1;
                    if (ms == 0) {
                        e0 = st0[(2*kl+0)*4 + 2*wl]; e1 = st0[(2*kl+0)*4 + 2*wl + 1];
                        f0 = st0[(2*kl+1)*4 + 2*wl]; f1 = st0[(2*kl+1)*4 + 2*wl + 1];
                    } else {
                        e0 = st1[(2*kl+0)*4 + 2*wl]; e1 = st1[(2*kl+0)*4 + 2*wl + 1];
                        f0 = st1[(2*kl+1)*4 + 2*wl]; f1 = st1[(2*kl+1)*4 + 2*wl + 1];
                    }
                    unsigned a = cvtpk(e0, e1);
                    unsigned c = cvtpk(f0, f1);
                    swap32(a, c);
                    pbw[ms * 2 + kl][wl]     = a;
                    pbw[ms * 2 + kl][2 + wl] = c;
                }
            }
        }
        {
            union { unsigned u[4]; v8s v; } f;
            f.u[0]=pbw[0][0]; f.u[1]=pbw[0][1]; f.u[2]=pbw[0][2]; f.u[3]=pbw[0][3]; pbP0=f.v;
            f.u[0]=pbw[1][0]; f.u[1]=pbw[1][1]; f.u[2]=pbw[1][2]; f.u[3]=pbw[1][3]; pbP1=f.v;
            f.u[0]=pbw[2][0]; f.u[1]=pbw[2][1]; f.u[2]=pbw[2][2]; f.u[3]=pbw[2][3]; pbP2=f.v;
            f.u[0]=pbw[3][0]; f.u[1]=pbw[3][1]; f.u[2]=pbw[3][2]; f.u[3]=pbw[3][3]; pbP3=f.v;
        }

        __syncthreads();   // DMA(it+1) drained; ring slot rotation safe (4-deep)
        kc0a = kn0a; kc0b = kn0b; kc1a = kn1a; kc1b = kn1b;
    }

    // ---- epilogue PV(NT-1) ----
    {
        const char* vbse = (const char*)&Vs[(NT - 1) & 3][0][0];
        v8s a00 = *(const v8s*)(vbse + (cl << 7) + sx0);
        v8s a10 = *(const v8s*)(vbse + ((32 + cl) << 7) + sx0);
        v8s a01 = *(const v8s*)(vbse + (cl << 7) + sx1);
        v8s a11 = *(const v8s*)(vbse + ((32 + cl) << 7) + sx1);
        v8s a02 = *(const v8s*)(vbse + (cl << 7) + sx2);
        v8s a12 = *(const v8s*)(vbse + ((32 + cl) << 7) + sx2);
        v8s a03 = *(const v8s*)(vbse + (cl << 7) + sx3);
        v8s a13 = *(const v8s*)(vbse + ((32 + cl) << 7) + sx3);
        acc0 = __builtin_amdgcn_mfma_f32_32x32x16_bf16(a00, pbP0, acc0, 0, 0, 0);
        acc1 = __builtin_amdgcn_mfma_f32_32x32x16_bf16(a10, pbP0, acc1, 0, 0, 0);
        acc0 = __builtin_amdgcn_mfma_f32_32x32x16_bf16(a01, pbP1, acc0, 0, 0, 0);
        acc1 = __builtin_amdgcn_mfma_f32_32x32x16_bf16(a11, pbP1, acc1, 0, 0, 0);
        acc0 = __builtin_amdgcn_mfma_f32_32x32x16_bf16(a02, pbP2, acc0, 0, 0, 0);
        acc1 = __builtin_amdgcn_mfma_f32_32x32x16_bf16(a12, pbP2, acc1, 0, 0, 0);
        acc0 = __builtin_amdgcn_mfma_f32_32x32x16_bf16(a03, pbP3, acc0, 0, 0, 0);
        acc1 = __builtin_amdgcn_mfma_f32_32x32x16_bf16(a13, pbP3, acc1, 0, 0, 0);
    }

    float l_tot = l_lane + __shfl_xor(l_lane, 32);
    const float il = 1.0f / l_tot;
    const float gm = gamma[0];
#pragma unroll
    for (int cs = 0; cs < 2; cs++) {
#pragma unroll
        for (int r = 0; r < 16; r++) {
            int c = ch * 64 + cs * 32 + (r & 3) + 8 * (r >> 2) + 4 * h;
            size_t idx = ((size_t)b * C_ + c) * N_ + q;
            float a = (cs == 0) ? acc0[r] : acc1[r];
            out[idx] = gm * (a * il) + x[idx];
        }
    }
}

extern "C" void kernel_launch(void* const* d_in, const int* in_sizes, int n_in,
                              void* d_out, int out_size, void* d_ws, size_t ws_size,
                              hipStream_t stream)
{
    const float* x  = (const float*)d_in[0];
    const float* Wb = (const float*)d_in[1];
    const float* bb = (const float*)d_in[2];
    const float* Wc = (const float*)d_in[3];
    const float* bc = (const float*)d_in[4];
    const float* Wd = (const float*)d_in[5];
    const float* bd = (const float*)d_in[6];
    const float* gm = (const float*)d_in[7];
    float* out = (float*)d_out;

    unsigned short* Qw = (unsigned short*)d_ws;
    unsigned short* Kw = Qw + (size_t)B_ * N_ * 32;
    unsigned short* Vw = Kw + (size_t)B_ * N_ * 32;
    unsigned short* Wcat = Vw + (size_t)B_ * C_ * N_;

    wcvt_kernel<<<dim3(80), 256, 0, stream>>>(Wb, Wc, Wd, Wcat);
    proj_mfma<<<dim3(N_ / 32, B_), 256, 0, stream>>>(x, Wcat, bb, bc, bd, Qw, Kw, Vw);
    attn_mfma<<<dim3(512), 256, 0, stream>>>(Qw, Kw, Vw, x, gm, out);
}